// Round 8
// baseline (235.928 us; speedup 1.0000x reference)
//
#include <hip/hip_runtime.h>
#include <math.h>

#define Nn 8192
#define Dd 256
#define Cc 16

// ---- workspace layout (floats) ----
// [0 .. 4M) : gemm1 bf16 partials (4 splits x Nn*Dd ushort = 16MB); later
//             gemm2 f32 partials (2M floats) reuse the front of it.
#define OFF_BP   4194304u    // bf16 packed B fragments (4 MB)
#define OFF_LOG  5242880u    // logits f32 8192*16
#define OFF_G1B  5373952u    // bf16[8192] (gamma-1)
#define OFF_DEN  5378048u    // 4*8192 f32
#define OFF_RS   5410816u    // 4*8192 f32
#define OFF_KC   5443584u    // 64
#define WS_FLOATS 5443648u

typedef short vshort8 __attribute__((ext_vector_type(8)));
typedef float vfloat4 __attribute__((ext_vector_type(4)));

#define AS1 __attribute__((address_space(1)))
#define AS3 __attribute__((address_space(3)))

__device__ __forceinline__ float clip1(float x) {
    return fminf(fmaxf(x, -1.0f + 1e-7f), 1.0f - 1e-7f);
}

__device__ __forceinline__ unsigned short f2bf(float f) {
    unsigned int u = __float_as_uint(f);
    u += 0x7fff + ((u >> 16) & 1);          // round-to-nearest-even
    return (unsigned short)(u >> 16);
}

__device__ __forceinline__ float bf2f(unsigned short b) {
    return __uint_as_float(((unsigned int)b) << 16);
}

__device__ __forceinline__ float waveReduce(float v) {
    #pragma unroll
    for (int off = 32; off; off >>= 1) v += __shfl_down(v, off);
    return v;
}

__device__ __forceinline__ float blockReduceBcast(float v, float* red) {
    int t = threadIdx.x, w = t >> 6, l = t & 63;
    v = waveReduce(v);
    if (l == 0) red[w] = v;
    __syncthreads();
    if (t == 0) red[0] = red[0] + red[1] + red[2] + red[3];
    __syncthreads();
    float r = red[0];
    __syncthreads();
    return r;
}

// ---- K0: per-prototype constants ----
__global__ __launch_bounds__(256) void k_consts(const float* __restrict__ Wl,
                                                const float* __restrict__ Pk,
                                                float* __restrict__ kc) {
    __shared__ float red[8];
    int t = threadIdx.x, k = blockIdx.x;
    float pv = Pk[k * Dd + t];
    float wv = Wl[t * Cc + k];
    float p2 = blockReduceBcast(pv * pv, red);
    float pw = blockReduceBcast(pv * wv, red);
    float w2 = blockReduceBcast(wv * wv, red);
    if (t == 0) {
        float an  = fmaxf(sqrtf(w2), 1e-15f);
        float lam = 2.0f / fmaxf(1.0f - p2, 1e-10f);
        kc[k * 4 + 0] = p2; kc[k * 4 + 1] = pw;
        kc[k * 4 + 2] = an; kc[k * 4 + 3] = lam;
    }
}

// ---- K1: fused X@W^T (bf16 MFMA) + mobius rescale + gamma -> packed B ----
// Block handles rows m0..m0+31 of G == k-slab s = blockIdx.x of gemm1's B.
// Bp chunk ((s*16 + g*4 + ni)*64 + lane) holds the vshort8 fragment for
// (col = g*64+ni*16+(lane&15), k = s*32+(lane>>4)*8+e).
__global__ __launch_bounds__(256) void k_front(const float* __restrict__ X,
                                               const float* __restrict__ W,
                                               unsigned short* __restrict__ Bp,
                                               unsigned short* __restrict__ g1b) {
    __shared__ __align__(16) unsigned short Xs[32][256];  // swizzled bf16 X tile
    __shared__ __align__(16) unsigned short Gs[32][258];  // padded [k-local][col]
    __shared__ float xs2[32];
    __shared__ float scal[32];
    __shared__ float red4[32][4];

    const int t = threadIdx.x;
    const int l = t & 63, w = t >> 6;
    const int ll = l & 15, kh = l >> 4;
    const int m0 = blockIdx.x * 32;
    const int ar = t >> 3, aq = t & 7;
    const int c0 = w * 64;

    float x2p = 0.f;
    #pragma unroll
    for (int tc = 0; tc < 4; ++tc) {
        const float* xp = &X[(size_t)(m0 + ar) * Dd + tc * 64 + aq * 8];
        vfloat4 v0 = *(const vfloat4*)xp;
        vfloat4 v1 = *(const vfloat4*)(xp + 4);
        vshort8 o;
        #pragma unroll
        for (int e = 0; e < 4; ++e) {
            x2p += v0[e] * v0[e] + v1[e] * v1[e];
            o[e] = (short)f2bf(v0[e]);
            o[e + 4] = (short)f2bf(v1[e]);
        }
        int byte = (tc * 64 + aq * 8) * 2;
        *(vshort8*)((char*)&Xs[ar][0] + (byte ^ ((ar & 7) << 4))) = o;
    }
    x2p += __shfl_xor(x2p, 1); x2p += __shfl_xor(x2p, 2); x2p += __shfl_xor(x2p, 4);
    if (aq == 0) xs2[ar] = x2p;
    __syncthreads();

    vfloat4 acc[2][4];
    #pragma unroll
    for (int mi = 0; mi < 2; ++mi)
        #pragma unroll
        for (int ni = 0; ni < 4; ++ni)
            acc[mi][ni] = (vfloat4){0.f, 0.f, 0.f, 0.f};
    #pragma unroll
    for (int tc = 0; tc < 4; ++tc) {
        vshort8 bf[8];
        #pragma unroll
        for (int ni = 0; ni < 4; ++ni)
            #pragma unroll
            for (int kk = 0; kk < 2; ++kk) {
                const float* wp = &W[(size_t)(c0 + ni * 16 + ll) * Dd
                                     + tc * 64 + kh * 8 + kk * 32];
                vfloat4 b0 = *(const vfloat4*)wp;
                vfloat4 b1 = *(const vfloat4*)(wp + 4);
                vshort8 o;
                #pragma unroll
                for (int e = 0; e < 4; ++e) {
                    o[e] = (short)f2bf(b0[e]);
                    o[e + 4] = (short)f2bf(b1[e]);
                }
                bf[ni * 2 + kk] = o;
            }
        #pragma unroll
        for (int kk = 0; kk < 2; ++kk) {
            int byte = (tc * 64 + kh * 8 + kk * 32) * 2;
            vshort8 af[2];
            #pragma unroll
            for (int mi = 0; mi < 2; ++mi) {
                int row = mi * 16 + ll;
                af[mi] = *(const vshort8*)((const char*)&Xs[row][0]
                                           + (byte ^ ((row & 7) << 4)));
            }
            #pragma unroll
            for (int mi = 0; mi < 2; ++mi)
                #pragma unroll
                for (int ni = 0; ni < 4; ++ni)
                    acc[mi][ni] = __builtin_amdgcn_mfma_f32_16x16x32_bf16(
                        af[mi], bf[ni * 2 + kk], acc[mi][ni], 0, 0, 0);
        }
    }

    #pragma unroll
    for (int mi = 0; mi < 2; ++mi)
        #pragma unroll
        for (int j = 0; j < 4; ++j) {
            float p = 0.f;
            #pragma unroll
            for (int ni = 0; ni < 4; ++ni)
                p += acc[mi][ni][j] * acc[mi][ni][j];
            p += __shfl_xor(p, 1); p += __shfl_xor(p, 2);
            p += __shfl_xor(p, 4); p += __shfl_xor(p, 8);
            if (ll == 0) red4[mi * 16 + kh * 4 + j][w] = p;
        }
    __syncthreads();

    if (t < 32) {
        float mx2 = red4[t][0] + red4[t][1] + red4[t][2] + red4[t][3];
        float xn = fmaxf(sqrtf(xs2[t]), 1e-15f);
        float mxn = fmaxf(sqrtf(mx2), 1e-15f);
        float s = tanhf(mxn / xn * atanhf(clip1(xn))) / mxn;
        float xw2 = s * s * mx2;                 // |xw|^2 = s^2 |mx|^2
        float gamma = 2.0f / fmaxf(1.0f - xw2, 1e-10f);
        scal[t] = gamma * s;
        g1b[m0 + t] = f2bf(gamma - 1.0f);
    }
    __syncthreads();

    #pragma unroll
    for (int mi = 0; mi < 2; ++mi)
        #pragma unroll
        for (int ni = 0; ni < 4; ++ni) {
            int row = mi * 16 + kh * 4;
            int col = c0 + ni * 16 + ll;
            #pragma unroll
            for (int j = 0; j < 4; ++j)
                Gs[row + j][col] = f2bf(scal[row + j] * acc[mi][ni][j]);
        }
    __syncthreads();

    const int s = blockIdx.x;
    #pragma unroll
    for (int pass = 0; pass < 4; ++pass) {
        int c = pass * 256 + t;
        int gni = c >> 6, lc = c & 63;
        int col = (gni >> 2) * 64 + (gni & 3) * 16 + (lc & 15);
        int kh8 = (lc >> 4) * 8;
        vshort8 o;
        #pragma unroll
        for (int e = 0; e < 8; ++e) o[e] = (short)Gs[kh8 + e][col];
        *(vshort8*)&Bp[((size_t)(s * 16 + gni) * 64 + lc) * 8] = o;
    }
}

// ======== K2 helpers ========
__device__ __forceinline__ void g1_issueB(const unsigned short* __restrict__ Bp,
        unsigned short (&Bs)[2][16][512], int bbuf, int splt, int slab,
        int w, int l) {
    #pragma unroll
    for (int ni = 0; ni < 4; ++ni)
        __builtin_amdgcn_global_load_lds(
            (const AS1 unsigned int*)
                (Bp + ((size_t)((splt * 64 + slab) * 16 + w * 4 + ni) * 512) + l * 8),
            (AS3 unsigned int*)&Bs[bbuf][w * 4 + ni][0], 16, 0, 0);
}

__device__ __forceinline__ void g1_issueA(const float* const (&asrc)[2],
        float (&As)[4][2048], int buf, int w, int tile) {
    #pragma unroll
    for (int i = 0; i < 2; ++i)
        __builtin_amdgcn_global_load_lds(
            (const AS1 unsigned int*)(asrc[i] + tile * 32),
            (AS3 unsigned int*)&As[buf][i * 1024 + w * 256], 16, 0, 0);
}

__device__ __forceinline__ void g1_phase(const float (&As)[4][2048],
        const unsigned short (&Bs)[2][16][512], const unsigned short* g1s,
        int cur, int bbuf, int p, int w, int kh, int ll15, int l,
        vfloat4 (&acc)[4][4], float (&dacc)[4], float (&racc)[4]) {
    vshort8 gv = {};
    if (w == 0) gv = *(const vshort8*)&g1s[p * 32 + kh * 8];
    vshort8 bf[4];
    #pragma unroll
    for (int ni = 0; ni < 4; ++ni)
        bf[ni] = *(const vshort8*)&Bs[bbuf][w * 4 + ni][l * 8];
    vshort8 af[4];
    #pragma unroll
    for (int mi = 0; mi < 4; ++mi) {
        int row = mi * 16 + ll15;
        int ba = row * 128 + (((kh * 2) ^ (row & 7)) << 4);
        vfloat4 v0 = *(const vfloat4*)((const char*)&As[cur][0] + ba);
        vfloat4 v1 = *(const vfloat4*)((const char*)&As[cur][0] + (ba ^ 16));
        vshort8 o;
        #pragma unroll
        for (int e = 0; e < 4; ++e) {
            o[e] = (short)f2bf(v0[e]);
            o[e + 4] = (short)f2bf(v1[e]);
        }
        af[mi] = o;
        if (w == 0) {
            #pragma unroll
            for (int e = 0; e < 4; ++e) {
                dacc[mi] += v0[e] * bf2f((unsigned short)gv[e])
                          + v1[e] * bf2f((unsigned short)gv[e + 4]);
                racc[mi] += v0[e] + v1[e];
            }
        }
    }
    #pragma unroll
    for (int mi = 0; mi < 4; ++mi)
        #pragma unroll
        for (int ni = 0; ni < 4; ++ni)
            acc[mi][ni] = __builtin_amdgcn_mfma_f32_16x16x32_bf16(
                af[mi], bf[ni], acc[mi][ni], 0, 0, 0);
}

// ---- K2: bf16 partials[split] = A(k-slice) @ G ----
// BM=64, BN=256, BK=32, S=4 -> 512 blocks (2/CU). ALL loads are
// global_load_lds (A 4-deep ring, B 2-deep; packed coalesced B chunks).
// No reg-dest VMEM -> hand-counted vmcnt(8/6/4/0) is the only pacing;
// raw s_barrier per phase (no drain).
__global__ __launch_bounds__(256, 2) void k_gemm1_mfma(
        const float* __restrict__ A,
        const unsigned short* __restrict__ Bp,
        const unsigned short* __restrict__ g1b,
        unsigned short* __restrict__ Pp,
        float* __restrict__ denp,
        float* __restrict__ rsp) {
    __shared__ __align__(16) float As[4][2048];             // 32 KB (4 x 64x32)
    __shared__ __align__(16) unsigned short Bs[2][16][512]; // 32 KB
    __shared__ __align__(16) unsigned short g1s[2048];      // 4 KB

    const int t = threadIdx.x, l = t & 63, w = t >> 6;
    const int id = blockIdx.x;
    const int splt = id & 3;                 // constant per XCD (id%8)
    const int m0 = (id >> 2) * 64;
    const int kb = splt * 2048;
    const int kh = l >> 4, ll15 = l & 15;

    // A gload sources: thread covers chunk q = i*256+t; row=q>>3, c=q&7 (swz src)
    const float* asrc[2];
    #pragma unroll
    for (int i = 0; i < 2; ++i) {
        int q = i * 256 + t;
        int row = q >> 3, c = q & 7;
        asrc[i] = &A[(size_t)(m0 + row) * Nn + kb + ((c ^ (row & 7)) << 2)];
    }

    vfloat4 acc[4][4];
    #pragma unroll
    for (int mi = 0; mi < 4; ++mi)
        #pragma unroll
        for (int ni = 0; ni < 4; ++ni)
            acc[mi][ni] = (vfloat4){0.f, 0.f, 0.f, 0.f};
    float dacc[4] = {0.f, 0.f, 0.f, 0.f}, racc[4] = {0.f, 0.f, 0.f, 0.f};

    // ---- prologue: g1 slice; B(0); A tiles 0,1,2 ----
    {
        uint4 g1v = *(const uint4*)&g1b[kb + t * 8];
        *(uint4*)&g1s[t * 8] = g1v;
        g1_issueB(Bp, Bs, 0, splt, 0, w, l);
        g1_issueA(asrc, As, 0, w, 0);
        g1_issueA(asrc, As, 1, w, 1);
        g1_issueA(asrc, As, 2, w, 2);
        asm volatile("s_waitcnt vmcnt(4) lgkmcnt(0)" ::: "memory");
        __builtin_amdgcn_s_barrier();
        __builtin_amdgcn_sched_barrier(0);
    }

    // ---- main: p = 0..59 (issue B(p+1), A t(p+3); wait vmcnt(8)) ----
    for (int u = 0; u < 15; ++u) {
        #pragma unroll
        for (int pp = 0; pp < 4; ++pp) {
            const int p = u * 4 + pp;
            g1_issueB(Bp, Bs, (pp & 1) ^ 1, splt, p + 1, w, l);
            g1_issueA(asrc, As, (pp + 3) & 3, w, p + 3);
            asm volatile("s_waitcnt vmcnt(8)" ::: "memory");
            g1_phase(As, Bs, g1s, pp, pp & 1, p, w, kh, ll15, l, acc, dacc, racc);
            __builtin_amdgcn_s_barrier();
            __builtin_amdgcn_sched_barrier(0);
        }
    }
    // ---- tail: p = 60..63 ----
    g1_issueB(Bp, Bs, 1, splt, 61, w, l);
    g1_issueA(asrc, As, 3, w, 63);
    asm volatile("s_waitcnt vmcnt(8)" ::: "memory");
    g1_phase(As, Bs, g1s, 0, 0, 60, w, kh, ll15, l, acc, dacc, racc);
    __builtin_amdgcn_s_barrier();
    __builtin_amdgcn_sched_barrier(0);

    g1_issueB(Bp, Bs, 0, splt, 62, w, l);
    asm volatile("s_waitcnt vmcnt(6)" ::: "memory");
    g1_phase(As, Bs, g1s, 1, 1, 61, w, kh, ll15, l, acc, dacc, racc);
    __builtin_amdgcn_s_barrier();
    __builtin_amdgcn_sched_barrier(0);

    g1_issueB(Bp, Bs, 1, splt, 63, w, l);
    asm volatile("s_waitcnt vmcnt(4)" ::: "memory");
    g1_phase(As, Bs, g1s, 2, 0, 62, w, kh, ll15, l, acc, dacc, racc);
    __builtin_amdgcn_s_barrier();
    __builtin_amdgcn_sched_barrier(0);

    asm volatile("s_waitcnt vmcnt(0)" ::: "memory");
    g1_phase(As, Bs, g1s, 3, 1, 63, w, kh, ll15, l, acc, dacc, racc);

    // ---- den/rs (wave 0 saw every (row,k) exactly once) ----
    if (w == 0) {
        #pragma unroll
        for (int mi = 0; mi < 4; ++mi) {
            dacc[mi] += __shfl_xor(dacc[mi], 16);
            dacc[mi] += __shfl_xor(dacc[mi], 32);
            racc[mi] += __shfl_xor(racc[mi], 16);
            racc[mi] += __shfl_xor(racc[mi], 32);
        }
        if (l < 16) {
            #pragma unroll
            for (int mi = 0; mi < 4; ++mi) {
                denp[splt * Nn + m0 + mi * 16 + l] = dacc[mi];
                rsp [splt * Nn + m0 + mi * 16 + l] = racc[mi];
            }
        }
    }

    // ---- store bf16 partial ----
    unsigned short* P = Pp + (size_t)splt * ((size_t)Nn * Dd);
    #pragma unroll
    for (int mi = 0; mi < 4; ++mi)
        #pragma unroll
        for (int ni = 0; ni < 4; ++ni) {
            int row = m0 + mi * 16 + (kh << 2);
            int col = w * 64 + ni * 16 + ll15;
            #pragma unroll
            for (int j = 0; j < 4; ++j)
                P[(size_t)(row + j) * Dd + col] = f2bf(acc[mi][ni][j]);
        }
}

// ---- K3: per-row gyromidpoint chain + H1 + hyperbolic logits ----
__global__ __launch_bounds__(256) void k_rowfix(const unsigned short* __restrict__ Pp,
                                                const float* __restrict__ denp,
                                                const float* __restrict__ rsp,
                                                const float* __restrict__ Pk,
                                                const float* __restrict__ Wl,
                                                const float* __restrict__ kc,
                                                float* __restrict__ logits) {
    __shared__ float red[8];
    __shared__ float hs[256];
    __shared__ float PQ[16][2];
    int i = blockIdx.x, t = threadIdx.x;
    float nom = 0.f;
    #pragma unroll
    for (int s = 0; s < 4; ++s)
        nom += bf2f(Pp[(size_t)s * Nn * Dd + (size_t)i * Dd + t]);
    float dv = denp[i] + denp[Nn + i] + denp[2 * Nn + i] + denp[3 * Nn + i];
    dv = (fabsf(dv) < 1e-10f) ? 1e-10f : dv;
    float tm = nom / dv;
    float r2 = blockReduceBcast(tm * tm, red);
    float r = fmaxf(sqrtf(r2), 1e-15f);
    float mmul = tanhf(0.5f * atanhf(clip1(r))) / r;
    float mj = mmul * tm;
    float mn2 = blockReduceBcast(mj * mj, red);
    float mn = fmaxf(sqrtf(mn2), 1e-15f);
    float sA = rsp[i] + rsp[Nn + i] + rsp[2 * Nn + i] + rsp[3 * Nn + i];
    float axmul = tanhf(sA * atanhf(clip1(mn))) / mn;
    float axw = axmul * mj;
    float yn2 = blockReduceBcast(axw * axw, red);
    float yn = fmaxf(sqrtf(yn2), 1e-15f);
    float v = atanhf(clip1(yn)) / yn * axw;
    float u = fmaxf(v, 0.0f);
    float un2 = blockReduceBcast(u * u, red);
    float un = fmaxf(sqrtf(un2), 1e-15f);
    float h = tanhf(un) / un * u;
    float h2 = blockReduceBcast(h * h, red);
    hs[t] = h;
    __syncthreads();
    int w = t >> 6, l = t & 63;
    #pragma unroll
    for (int kk = 0; kk < 4; ++kk) {
        int k = w * 4 + kk;
        float pp = 0.f, qq = 0.f;
        #pragma unroll
        for (int m = 0; m < 4; ++m) {
            float hv = hs[l + 64 * m];
            pp += hv * Pk[k * Dd + l + 64 * m];
            qq += hv * Wl[(l + 64 * m) * Cc + k];
        }
        pp = waveReduce(pp);
        qq = waveReduce(qq);
        if (l == 0) { PQ[k][0] = pp; PQ[k][1] = qq; }
    }
    __syncthreads();
    if (t < 16) {
        int k = t;
        float p2 = kc[k * 4 + 0], pw = kc[k * 4 + 1];
        float an = kc[k * 4 + 2], lam = kc[k * 4 + 3];
        float P = PQ[k][0], Q = PQ[k][1];
        float alpha = 1.0f - 2.0f * P + h2;
        float beta  = 1.0f - p2;
        float Dm = fmaxf(1.0f - 2.0f * P + p2 * h2, 1e-15f);
        float za  = (-alpha * pw + beta * Q) / Dm;
        float zn2 = (alpha * alpha * p2 - 2.0f * alpha * beta * P + beta * beta * h2)
                    / (Dm * Dm);
        float dd = fmaxf(1.0f - zn2, 1e-10f) * an;
        float dist = asinhf(2.0f * za / dd);
        logits[(size_t)i * Cc + k] = lam * an * dist;
    }
}

// ---- K4: partials of out = A @ logits (j-split x16) ----
__global__ __launch_bounds__(256) void k_gemm2(const float* __restrict__ A,
                                               const float* __restrict__ L,
                                               float* __restrict__ part) {
    __shared__ __align__(16) float Ls[64 * 20];
    __shared__ float Pacc[256 * 16];
    int t = threadIdx.x;
    int r0 = blockIdx.x * 256;
    int jbase = blockIdx.y * 512;
    int q = t & 3, g = t >> 2;
    float acc[4][16] = {};
    for (int jc = 0; jc < 512; jc += 64) {
        {
            int jrow = t >> 2, kq = t & 3;
            *(float4*)&Ls[jrow * 20 + kq * 4] =
                *(const float4*)&L[(size_t)(jbase + jc + jrow) * Cc + kq * 4];
        }
        __syncthreads();
        #pragma unroll
        for (int m = 0; m < 4; ++m) {
            int jl = m * 16 + q * 4;
            float av[4][4];
            #pragma unroll
            for (int rr = 0; rr < 4; ++rr) {
                float4 tmp = *(const float4*)&A[(size_t)(r0 + g * 4 + rr) * Nn
                                                + jbase + jc + jl];
                av[rr][0] = tmp.x; av[rr][1] = tmp.y;
                av[rr][2] = tmp.z; av[rr][3] = tmp.w;
            }
            #pragma unroll
            for (int jj = 0; jj < 4; ++jj) {
                const float* lr = &Ls[(jl + jj) * 20];
                float lv[16];
                #pragma unroll
                for (int k2 = 0; k2 < 16; k2 += 4) {
                    float4 lt = *(const float4*)&lr[k2];
                    lv[k2] = lt.x; lv[k2 + 1] = lt.y;
                    lv[k2 + 2] = lt.z; lv[k2 + 3] = lt.w;
                }
                #pragma unroll
                for (int rr = 0; rr < 4; ++rr)
                    #pragma unroll
                    for (int k2 = 0; k2 < 16; ++k2)
                        acc[rr][k2] += av[rr][jj] * lv[k2];
            }
        }
        __syncthreads();
    }
    for (int ii = t; ii < 4096; ii += 256) Pacc[ii] = 0.f;
    __syncthreads();
    for (int qq = 0; qq < 4; ++qq) {
        if (q == qq) {
            #pragma unroll
            for (int rr = 0; rr < 4; ++rr)
                #pragma unroll
                for (int k2 = 0; k2 < 16; ++k2)
                    Pacc[(g * 4 + rr) * 16 + k2] += acc[rr][k2];
        }
        __syncthreads();
    }
    float* dst = &part[(size_t)blockIdx.y * (Nn * Cc) + (size_t)r0 * Cc];
    for (int ii = t * 4; ii < 4096; ii += 1024)
        *(float4*)&dst[ii] = *(const float4*)&Pacc[ii];
}

// ---- K5: reduce j-split partials ----
__global__ __launch_bounds__(256) void k_reduce(const float* __restrict__ part,
                                                float* __restrict__ out) {
    int i = blockIdx.x * 256 + threadIdx.x;
    float s = 0.f;
    #pragma unroll
    for (int j = 0; j < 16; ++j) s += part[(size_t)j * (Nn * Cc) + i];
    out[i] = s;
}

extern "C" void kernel_launch(void* const* d_in, const int* in_sizes, int n_in,
                              void* d_out, int out_size, void* d_ws, size_t ws_size,
                              hipStream_t stream) {
    const float* X  = (const float*)d_in[0];
    const float* A  = (const float*)d_in[1];
    const float* W  = (const float*)d_in[2];
    const float* Wl = (const float*)d_in[3];
    const float* Pk = (const float*)d_in[4];
    float* out = (float*)d_out;
    float* ws = (float*)d_ws;
    if (ws_size < (size_t)WS_FLOATS * sizeof(float)) return;

    unsigned short* Pp  = (unsigned short*)ws;      // 4 bf16 partials (16MB)
    float* part = ws;                               // gemm2 f32 partials (8MB, later)
    unsigned short* Bp  = (unsigned short*)(ws + OFF_BP);
    float* lg   = ws + OFF_LOG;
    unsigned short* g1b = (unsigned short*)(ws + OFF_G1B);
    float* denp = ws + OFF_DEN;
    float* rsp  = ws + OFF_RS;
    float* kc   = ws + OFF_KC;

    k_consts<<<16, 256, 0, stream>>>(Wl, Pk, kc);
    k_front<<<256, 256, 0, stream>>>(X, W, Bp, g1b);
    k_gemm1_mfma<<<512, 256, 0, stream>>>(A, Bp, g1b, Pp, denp, rsp);
    k_rowfix<<<Nn, 256, 0, stream>>>(Pp, denp, rsp, Pk, Wl, kc, lg);
    k_gemm2<<<dim3(32, 16), 256, 0, stream>>>(A, lg, part);
    k_reduce<<<512, 256, 0, stream>>>(part, out);
}

// Round 9
// 220.409 us; speedup vs baseline: 1.0704x; 1.0704x over previous
//
#include <hip/hip_runtime.h>
#include <math.h>

#define Nn 8192
#define Dd 256
#define Cc 16

// ---- workspace layout (floats) ----
// [0 .. 4M) : gemm1 bf16 partials (4 splits x Nn*Dd ushort = 16MB); later
//             gemm2 f32 partials (2M floats) reuse the front of it.
#define OFF_BP   4194304u    // bf16 packed B fragments (4 MB)
#define OFF_LOG  5242880u    // logits f32 8192*16
#define OFF_G1B  5373952u    // bf16[8192] (gamma-1)
#define OFF_DEN  5378048u    // 4*8192 f32
#define OFF_RS   5410816u    // 4*8192 f32
#define OFF_KC   5443584u    // 64
#define WS_FLOATS 5443648u

typedef short vshort8 __attribute__((ext_vector_type(8)));
typedef float vfloat4 __attribute__((ext_vector_type(4)));

#define AS1 __attribute__((address_space(1)))
#define AS3 __attribute__((address_space(3)))

__device__ __forceinline__ float clip1(float x) {
    return fminf(fmaxf(x, -1.0f + 1e-7f), 1.0f - 1e-7f);
}

__device__ __forceinline__ unsigned short f2bf(float f) {
    unsigned int u = __float_as_uint(f);
    u += 0x7fff + ((u >> 16) & 1);          // round-to-nearest-even
    return (unsigned short)(u >> 16);
}

__device__ __forceinline__ float bf2f(unsigned short b) {
    return __uint_as_float(((unsigned int)b) << 16);
}

__device__ __forceinline__ float waveReduce(float v) {
    #pragma unroll
    for (int off = 32; off; off >>= 1) v += __shfl_down(v, off);
    return v;
}

__device__ __forceinline__ float blockReduceBcast(float v, float* red) {
    int t = threadIdx.x, w = t >> 6, l = t & 63;
    v = waveReduce(v);
    if (l == 0) red[w] = v;
    __syncthreads();
    if (t == 0) red[0] = red[0] + red[1] + red[2] + red[3];
    __syncthreads();
    float r = red[0];
    __syncthreads();
    return r;
}

// ---- K0: per-prototype constants ----
__global__ __launch_bounds__(256) void k_consts(const float* __restrict__ Wl,
                                                const float* __restrict__ Pk,
                                                float* __restrict__ kc) {
    __shared__ float red[8];
    int t = threadIdx.x, k = blockIdx.x;
    float pv = Pk[k * Dd + t];
    float wv = Wl[t * Cc + k];
    float p2 = blockReduceBcast(pv * pv, red);
    float pw = blockReduceBcast(pv * wv, red);
    float w2 = blockReduceBcast(wv * wv, red);
    if (t == 0) {
        float an  = fmaxf(sqrtf(w2), 1e-15f);
        float lam = 2.0f / fmaxf(1.0f - p2, 1e-10f);
        kc[k * 4 + 0] = p2; kc[k * 4 + 1] = pw;
        kc[k * 4 + 2] = an; kc[k * 4 + 3] = lam;
    }
}

// ---- K1: fused X@W^T (bf16 MFMA) + mobius rescale + gamma -> packed B ----
// Block handles rows m0..m0+31 of G == k-slab s = blockIdx.x of gemm1's B.
// Bp chunk ((s*16 + g*4 + ni)*64 + lane) holds the vshort8 fragment for
// (col = g*64+ni*16+(lane&15), k = s*32+(lane>>4)*8+e).
__global__ __launch_bounds__(256) void k_front(const float* __restrict__ X,
                                               const float* __restrict__ W,
                                               unsigned short* __restrict__ Bp,
                                               unsigned short* __restrict__ g1b) {
    __shared__ __align__(16) unsigned short Xs[32][256];  // swizzled bf16 X tile
    __shared__ __align__(16) unsigned short Gs[32][258];  // padded [k-local][col]
    __shared__ float xs2[32];
    __shared__ float scal[32];
    __shared__ float red4[32][4];

    const int t = threadIdx.x;
    const int l = t & 63, w = t >> 6;
    const int ll = l & 15, kh = l >> 4;
    const int m0 = blockIdx.x * 32;
    const int ar = t >> 3, aq = t & 7;
    const int c0 = w * 64;

    float x2p = 0.f;
    #pragma unroll
    for (int tc = 0; tc < 4; ++tc) {
        const float* xp = &X[(size_t)(m0 + ar) * Dd + tc * 64 + aq * 8];
        vfloat4 v0 = *(const vfloat4*)xp;
        vfloat4 v1 = *(const vfloat4*)(xp + 4);
        vshort8 o;
        #pragma unroll
        for (int e = 0; e < 4; ++e) {
            x2p += v0[e] * v0[e] + v1[e] * v1[e];
            o[e] = (short)f2bf(v0[e]);
            o[e + 4] = (short)f2bf(v1[e]);
        }
        int byte = (tc * 64 + aq * 8) * 2;
        *(vshort8*)((char*)&Xs[ar][0] + (byte ^ ((ar & 7) << 4))) = o;
    }
    x2p += __shfl_xor(x2p, 1); x2p += __shfl_xor(x2p, 2); x2p += __shfl_xor(x2p, 4);
    if (aq == 0) xs2[ar] = x2p;
    __syncthreads();

    vfloat4 acc[2][4];
    #pragma unroll
    for (int mi = 0; mi < 2; ++mi)
        #pragma unroll
        for (int ni = 0; ni < 4; ++ni)
            acc[mi][ni] = (vfloat4){0.f, 0.f, 0.f, 0.f};
    #pragma unroll
    for (int tc = 0; tc < 4; ++tc) {
        vshort8 bf[8];
        #pragma unroll
        for (int ni = 0; ni < 4; ++ni)
            #pragma unroll
            for (int kk = 0; kk < 2; ++kk) {
                const float* wp = &W[(size_t)(c0 + ni * 16 + ll) * Dd
                                     + tc * 64 + kh * 8 + kk * 32];
                vfloat4 b0 = *(const vfloat4*)wp;
                vfloat4 b1 = *(const vfloat4*)(wp + 4);
                vshort8 o;
                #pragma unroll
                for (int e = 0; e < 4; ++e) {
                    o[e] = (short)f2bf(b0[e]);
                    o[e + 4] = (short)f2bf(b1[e]);
                }
                bf[ni * 2 + kk] = o;
            }
        #pragma unroll
        for (int kk = 0; kk < 2; ++kk) {
            int byte = (tc * 64 + kh * 8 + kk * 32) * 2;
            vshort8 af[2];
            #pragma unroll
            for (int mi = 0; mi < 2; ++mi) {
                int row = mi * 16 + ll;
                af[mi] = *(const vshort8*)((const char*)&Xs[row][0]
                                           + (byte ^ ((row & 7) << 4)));
            }
            #pragma unroll
            for (int mi = 0; mi < 2; ++mi)
                #pragma unroll
                for (int ni = 0; ni < 4; ++ni)
                    acc[mi][ni] = __builtin_amdgcn_mfma_f32_16x16x32_bf16(
                        af[mi], bf[ni * 2 + kk], acc[mi][ni], 0, 0, 0);
        }
    }

    #pragma unroll
    for (int mi = 0; mi < 2; ++mi)
        #pragma unroll
        for (int j = 0; j < 4; ++j) {
            float p = 0.f;
            #pragma unroll
            for (int ni = 0; ni < 4; ++ni)
                p += acc[mi][ni][j] * acc[mi][ni][j];
            p += __shfl_xor(p, 1); p += __shfl_xor(p, 2);
            p += __shfl_xor(p, 4); p += __shfl_xor(p, 8);
            if (ll == 0) red4[mi * 16 + kh * 4 + j][w] = p;
        }
    __syncthreads();

    if (t < 32) {
        float mx2 = red4[t][0] + red4[t][1] + red4[t][2] + red4[t][3];
        float xn = fmaxf(sqrtf(xs2[t]), 1e-15f);
        float mxn = fmaxf(sqrtf(mx2), 1e-15f);
        float s = tanhf(mxn / xn * atanhf(clip1(xn))) / mxn;
        float xw2 = s * s * mx2;                 // |xw|^2 = s^2 |mx|^2
        float gamma = 2.0f / fmaxf(1.0f - xw2, 1e-10f);
        scal[t] = gamma * s;
        g1b[m0 + t] = f2bf(gamma - 1.0f);
    }
    __syncthreads();

    #pragma unroll
    for (int mi = 0; mi < 2; ++mi)
        #pragma unroll
        for (int ni = 0; ni < 4; ++ni) {
            int row = mi * 16 + kh * 4;
            int col = c0 + ni * 16 + ll;
            #pragma unroll
            for (int j = 0; j < 4; ++j)
                Gs[row + j][col] = f2bf(scal[row + j] * acc[mi][ni][j]);
        }
    __syncthreads();

    const int s = blockIdx.x;
    #pragma unroll
    for (int pass = 0; pass < 4; ++pass) {
        int c = pass * 256 + t;
        int gni = c >> 6, lc = c & 63;
        int col = (gni >> 2) * 64 + (gni & 3) * 16 + (lc & 15);
        int kh8 = (lc >> 4) * 8;
        vshort8 o;
        #pragma unroll
        for (int e = 0; e < 8; ++e) o[e] = (short)Gs[kh8 + e][col];
        *(vshort8*)&Bp[((size_t)(s * 16 + gni) * 64 + lc) * 8] = o;
    }
}

// ======== K2 helpers ========
__device__ __forceinline__ void g2_issueB(const unsigned short* __restrict__ Bp,
        unsigned short (&BsB)[16][512], int splt, int slab, int w, int l) {
    #pragma unroll
    for (int ni = 0; ni < 4; ++ni)
        __builtin_amdgcn_global_load_lds(
            (const AS1 unsigned int*)
                (Bp + ((size_t)((splt * 64 + slab) * 16 + w * 4 + ni) * 512) + l * 8),
            (AS3 unsigned int*)&BsB[w * 4 + ni][0], 16, 0, 0);
}

__device__ __forceinline__ void g2_loadA(const float* __restrict__ Abase,
                                         int tile, float (&a8)[8]) {
    const vfloat4* p = (const vfloat4*)(Abase + tile * 32);
    *(vfloat4*)&a8[0] = p[0];
    *(vfloat4*)&a8[4] = p[1];
}

// convert fp32 A regs -> bf16 LDS tile (once per element) + den/rs fold
__device__ __forceinline__ void g2_stage(unsigned short (&AsB)[2048],
        const unsigned short* g1s, const float (&a8)[8],
        int tile, int rowst, int kq, float& dacc, float& racc) {
    vshort8 gv = *(const vshort8*)&g1s[tile * 32 + kq * 8];
    vshort8 o;
    #pragma unroll
    for (int e = 0; e < 8; ++e) {
        float av = a8[e];
        o[e] = (short)f2bf(av);
        dacc += av * bf2f((unsigned short)gv[e]);
        racc += av;
    }
    *(vshort8*)((char*)&AsB[0] + rowst * 64 + ((kq * 16) ^ ((rowst & 3) << 4))) = o;
}

__device__ __forceinline__ void g2_mfma(const unsigned short (&AsB)[2048],
        const unsigned short (&BsB)[16][512], int w, int kh, int ll15, int l,
        vfloat4 (&acc)[4][4]) {
    vshort8 bf[4], af[4];
    #pragma unroll
    for (int ni = 0; ni < 4; ++ni)
        bf[ni] = *(const vshort8*)&BsB[w * 4 + ni][l * 8];
    #pragma unroll
    for (int mi = 0; mi < 4; ++mi) {
        int row = mi * 16 + ll15;
        af[mi] = *(const vshort8*)((const char*)&AsB[0]
                  + row * 64 + ((kh * 16) ^ ((row & 3) << 4)));
    }
    #pragma unroll
    for (int mi = 0; mi < 4; ++mi)
        #pragma unroll
        for (int ni = 0; ni < 4; ++ni)
            acc[mi][ni] = __builtin_amdgcn_mfma_f32_16x16x32_bf16(
                af[mi], bf[ni], acc[mi][ni], 0, 0, 0);
}

// ---- K2: bf16 partials[split] = A(k-slice) @ G ----
// BM=64, BN=256, BK=32, S=4 -> 512 blocks. A: regs -> f2bf once -> bf16 LDS
// (dbuf 2x4KB, slot-XOR swizzle). B: packed gload_lds (dbuf 2x16KB).
// FIFO = exactly 6 vmem ops/phase -> vmcnt(6) counted waits, raw s_barrier.
__global__ __launch_bounds__(256, 2) void k_gemm1_mfma(
        const float* __restrict__ A,
        const unsigned short* __restrict__ Bp,
        const unsigned short* __restrict__ g1b,
        unsigned short* __restrict__ Pp,
        float* __restrict__ denp,
        float* __restrict__ rsp) {
    __shared__ __align__(16) unsigned short As[2][2048];    // 8 KB (bf16 64x32 x2)
    __shared__ __align__(16) unsigned short Bs[2][16][512]; // 32 KB
    __shared__ __align__(16) unsigned short g1s[2048];      // 4 KB

    const int t = threadIdx.x, l = t & 63, w = t >> 6;
    const int id = blockIdx.x;
    const int splt = id & 3;                 // constant per XCD (id%8)
    const int m0 = (id >> 2) * 64;
    const int kb = splt * 2048;
    const int kh = l >> 4, ll15 = l & 15;
    const int rowst = t >> 2, kq = t & 3;    // staging: row, k-octet

    const float* Abase = &A[(size_t)(m0 + rowst) * Nn + kb + kq * 8];

    vfloat4 acc[4][4];
    #pragma unroll
    for (int mi = 0; mi < 4; ++mi)
        #pragma unroll
        for (int ni = 0; ni < 4; ++ni)
            acc[mi][ni] = (vfloat4){0.f, 0.f, 0.f, 0.f};
    float dacc = 0.f, racc = 0.f;
    float a0[8], a1[8];                      // A reg ring (distance 2)

    // ---- prologue: g1 -> LDS; B(0); A tiles 0,1 ----
    {
        uint4 g1v = *(const uint4*)&g1b[kb + t * 8];     // vm op #1
        *(uint4*)&g1s[t * 8] = g1v;
    }
    g2_issueB(Bp, Bs[0], splt, 0, w, l);                 // 4 gload_lds
    g2_loadA(Abase, 0, a0);                              // 2
    g2_loadA(Abase, 1, a1);                              // 2
    asm volatile("s_waitcnt lgkmcnt(0)" ::: "memory");
    __builtin_amdgcn_s_barrier();                        // g1s visible
    asm volatile("s_waitcnt vmcnt(2)" ::: "memory");     // a0 + B0 done (a1 flying)
    g2_stage(As[0], g1s, a0, 0, rowst, kq, dacc, racc);
    asm volatile("s_waitcnt lgkmcnt(0)" ::: "memory");
    __builtin_amdgcn_s_barrier();                        // As[0] visible
    __builtin_amdgcn_sched_barrier(0);

    // ---- main: p = 0..61 (2 phases/iter; literal buffer indices) ----
    for (int u = 0; u < 31; ++u) {
        const int p = u * 2;
        // even phase p: compute tile p from As[0]/Bs[0]
        g2_issueB(Bp, Bs[1], splt, p + 1, w, l);
        g2_loadA(Abase, p + 2, a0);
        asm volatile("s_waitcnt vmcnt(6)" ::: "memory"); // retire B(p), a(p+1)
        g2_stage(As[1], g1s, a1, p + 1, rowst, kq, dacc, racc);
        g2_mfma(As[0], Bs[0], w, kh, ll15, l, acc);
        asm volatile("s_waitcnt lgkmcnt(0)" ::: "memory");
        __builtin_amdgcn_s_barrier();
        __builtin_amdgcn_sched_barrier(0);
        // odd phase p+1: compute tile p+1 from As[1]/Bs[1]
        g2_issueB(Bp, Bs[0], splt, p + 2, w, l);
        g2_loadA(Abase, p + 3, a1);
        asm volatile("s_waitcnt vmcnt(6)" ::: "memory"); // retire B(p+1), a(p+2)
        g2_stage(As[0], g1s, a0, p + 2, rowst, kq, dacc, racc);
        g2_mfma(As[1], Bs[1], w, kh, ll15, l, acc);
        asm volatile("s_waitcnt lgkmcnt(0)" ::: "memory");
        __builtin_amdgcn_s_barrier();
        __builtin_amdgcn_sched_barrier(0);
    }
    // ---- tail p=62: entry outstanding [B62:4, a63:2] ----
    g2_issueB(Bp, Bs[1], splt, 63, w, l);
    asm volatile("s_waitcnt vmcnt(4)" ::: "memory");     // retire B62, a63
    g2_stage(As[1], g1s, a1, 63, rowst, kq, dacc, racc);
    g2_mfma(As[0], Bs[0], w, kh, ll15, l, acc);
    asm volatile("s_waitcnt lgkmcnt(0)" ::: "memory");
    __builtin_amdgcn_s_barrier();
    __builtin_amdgcn_sched_barrier(0);
    // ---- tail p=63 ----
    asm volatile("s_waitcnt vmcnt(0)" ::: "memory");
    g2_mfma(As[1], Bs[1], w, kh, ll15, l, acc);

    // ---- den/rs: 4 staging threads per row are adjacent lanes ----
    dacc += __shfl_xor(dacc, 1); dacc += __shfl_xor(dacc, 2);
    racc += __shfl_xor(racc, 1); racc += __shfl_xor(racc, 2);
    if (kq == 0) {
        denp[splt * Nn + m0 + rowst] = dacc;
        rsp [splt * Nn + m0 + rowst] = racc;
    }

    // ---- store bf16 partial ----
    unsigned short* P = Pp + (size_t)splt * ((size_t)Nn * Dd);
    #pragma unroll
    for (int mi = 0; mi < 4; ++mi)
        #pragma unroll
        for (int ni = 0; ni < 4; ++ni) {
            int row = m0 + mi * 16 + (kh << 2);
            int col = w * 64 + ni * 16 + ll15;
            #pragma unroll
            for (int j = 0; j < 4; ++j)
                P[(size_t)(row + j) * Dd + col] = f2bf(acc[mi][ni][j]);
        }
}

// ---- K3: per-row gyromidpoint chain + H1 + hyperbolic logits ----
__global__ __launch_bounds__(256) void k_rowfix(const unsigned short* __restrict__ Pp,
                                                const float* __restrict__ denp,
                                                const float* __restrict__ rsp,
                                                const float* __restrict__ Pk,
                                                const float* __restrict__ Wl,
                                                const float* __restrict__ kc,
                                                float* __restrict__ logits) {
    __shared__ float red[8];
    __shared__ float hs[256];
    __shared__ float PQ[16][2];
    int i = blockIdx.x, t = threadIdx.x;
    float nom = 0.f;
    #pragma unroll
    for (int s = 0; s < 4; ++s)
        nom += bf2f(Pp[(size_t)s * Nn * Dd + (size_t)i * Dd + t]);
    float dv = denp[i] + denp[Nn + i] + denp[2 * Nn + i] + denp[3 * Nn + i];
    dv = (fabsf(dv) < 1e-10f) ? 1e-10f : dv;
    float tm = nom / dv;
    float r2 = blockReduceBcast(tm * tm, red);
    float r = fmaxf(sqrtf(r2), 1e-15f);
    float mmul = tanhf(0.5f * atanhf(clip1(r))) / r;
    float mj = mmul * tm;
    float mn2 = blockReduceBcast(mj * mj, red);
    float mn = fmaxf(sqrtf(mn2), 1e-15f);
    float sA = rsp[i] + rsp[Nn + i] + rsp[2 * Nn + i] + rsp[3 * Nn + i];
    float axmul = tanhf(sA * atanhf(clip1(mn))) / mn;
    float axw = axmul * mj;
    float yn2 = blockReduceBcast(axw * axw, red);
    float yn = fmaxf(sqrtf(yn2), 1e-15f);
    float v = atanhf(clip1(yn)) / yn * axw;
    float u = fmaxf(v, 0.0f);
    float un2 = blockReduceBcast(u * u, red);
    float un = fmaxf(sqrtf(un2), 1e-15f);
    float h = tanhf(un) / un * u;
    float h2 = blockReduceBcast(h * h, red);
    hs[t] = h;
    __syncthreads();
    int w = t >> 6, l = t & 63;
    #pragma unroll
    for (int kk = 0; kk < 4; ++kk) {
        int k = w * 4 + kk;
        float pp = 0.f, qq = 0.f;
        #pragma unroll
        for (int m = 0; m < 4; ++m) {
            float hv = hs[l + 64 * m];
            pp += hv * Pk[k * Dd + l + 64 * m];
            qq += hv * Wl[(l + 64 * m) * Cc + k];
        }
        pp = waveReduce(pp);
        qq = waveReduce(qq);
        if (l == 0) { PQ[k][0] = pp; PQ[k][1] = qq; }
    }
    __syncthreads();
    if (t < 16) {
        int k = t;
        float p2 = kc[k * 4 + 0], pw = kc[k * 4 + 1];
        float an = kc[k * 4 + 2], lam = kc[k * 4 + 3];
        float P = PQ[k][0], Q = PQ[k][1];
        float alpha = 1.0f - 2.0f * P + h2;
        float beta  = 1.0f - p2;
        float Dm = fmaxf(1.0f - 2.0f * P + p2 * h2, 1e-15f);
        float za  = (-alpha * pw + beta * Q) / Dm;
        float zn2 = (alpha * alpha * p2 - 2.0f * alpha * beta * P + beta * beta * h2)
                    / (Dm * Dm);
        float dd = fmaxf(1.0f - zn2, 1e-10f) * an;
        float dist = asinhf(2.0f * za / dd);
        logits[(size_t)i * Cc + k] = lam * an * dist;
    }
}

// ---- K4: partials of out = A @ logits (j-split x16) ----
__global__ __launch_bounds__(256) void k_gemm2(const float* __restrict__ A,
                                               const float* __restrict__ L,
                                               float* __restrict__ part) {
    __shared__ __align__(16) float Ls[64 * 20];
    __shared__ float Pacc[256 * 16];
    int t = threadIdx.x;
    int r0 = blockIdx.x * 256;
    int jbase = blockIdx.y * 512;
    int q = t & 3, g = t >> 2;
    float acc[4][16] = {};
    for (int jc = 0; jc < 512; jc += 64) {
        {
            int jrow = t >> 2, kq2 = t & 3;
            *(float4*)&Ls[jrow * 20 + kq2 * 4] =
                *(const float4*)&L[(size_t)(jbase + jc + jrow) * Cc + kq2 * 4];
        }
        __syncthreads();
        #pragma unroll
        for (int m = 0; m < 4; ++m) {
            int jl = m * 16 + q * 4;
            float av[4][4];
            #pragma unroll
            for (int rr = 0; rr < 4; ++rr) {
                float4 tmp = *(const float4*)&A[(size_t)(r0 + g * 4 + rr) * Nn
                                                + jbase + jc + jl];
                av[rr][0] = tmp.x; av[rr][1] = tmp.y;
                av[rr][2] = tmp.z; av[rr][3] = tmp.w;
            }
            #pragma unroll
            for (int jj = 0; jj < 4; ++jj) {
                const float* lr = &Ls[(jl + jj) * 20];
                float lv[16];
                #pragma unroll
                for (int k2 = 0; k2 < 16; k2 += 4) {
                    float4 lt = *(const float4*)&lr[k2];
                    lv[k2] = lt.x; lv[k2 + 1] = lt.y;
                    lv[k2 + 2] = lt.z; lv[k2 + 3] = lt.w;
                }
                #pragma unroll
                for (int rr = 0; rr < 4; ++rr)
                    #pragma unroll
                    for (int k2 = 0; k2 < 16; ++k2)
                        acc[rr][k2] += av[rr][jj] * lv[k2];
            }
        }
        __syncthreads();
    }
    for (int ii = t; ii < 4096; ii += 256) Pacc[ii] = 0.f;
    __syncthreads();
    for (int qq = 0; qq < 4; ++qq) {
        if (q == qq) {
            #pragma unroll
            for (int rr = 0; rr < 4; ++rr)
                #pragma unroll
                for (int k2 = 0; k2 < 16; ++k2)
                    Pacc[(g * 4 + rr) * 16 + k2] += acc[rr][k2];
        }
        __syncthreads();
    }
    float* dst = &part[(size_t)blockIdx.y * (Nn * Cc) + (size_t)r0 * Cc];
    for (int ii = t * 4; ii < 4096; ii += 1024)
        *(float4*)&dst[ii] = *(const float4*)&Pacc[ii];
}

// ---- K5: reduce j-split partials ----
__global__ __launch_bounds__(256) void k_reduce(const float* __restrict__ part,
                                                float* __restrict__ out) {
    int i = blockIdx.x * 256 + threadIdx.x;
    float s = 0.f;
    #pragma unroll
    for (int j = 0; j < 16; ++j) s += part[(size_t)j * (Nn * Cc) + i];
    out[i] = s;
}

extern "C" void kernel_launch(void* const* d_in, const int* in_sizes, int n_in,
                              void* d_out, int out_size, void* d_ws, size_t ws_size,
                              hipStream_t stream) {
    const float* X  = (const float*)d_in[0];
    const float* A  = (const float*)d_in[1];
    const float* W  = (const float*)d_in[2];
    const float* Wl = (const float*)d_in[3];
    const float* Pk = (const float*)d_in[4];
    float* out = (float*)d_out;
    float* ws = (float*)d_ws;
    if (ws_size < (size_t)WS_FLOATS * sizeof(float)) return;

    unsigned short* Pp  = (unsigned short*)ws;      // 4 bf16 partials (16MB)
    float* part = ws;                               // gemm2 f32 partials (8MB, later)
    unsigned short* Bp  = (unsigned short*)(ws + OFF_BP);
    float* lg   = ws + OFF_LOG;
    unsigned short* g1b = (unsigned short*)(ws + OFF_G1B);
    float* denp = ws + OFF_DEN;
    float* rsp  = ws + OFF_RS;
    float* kc   = ws + OFF_KC;

    k_consts<<<16, 256, 0, stream>>>(Wl, Pk, kc);
    k_front<<<256, 256, 0, stream>>>(X, W, Bp, g1b);
    k_gemm1_mfma<<<512, 256, 0, stream>>>(A, Bp, g1b, Pp, denp, rsp);
    k_rowfix<<<Nn, 256, 0, stream>>>(Pp, denp, rsp, Pk, Wl, kc, lg);
    k_gemm2<<<dim3(32, 16), 256, 0, stream>>>(A, lg, part);
    k_reduce<<<512, 256, 0, stream>>>(part, out);
}

// Round 10
// 212.771 us; speedup vs baseline: 1.1088x; 1.0359x over previous
//
#include <hip/hip_runtime.h>
#include <math.h>

#define Nn 8192
#define Dd 256
#define Cc 16

// ---- workspace layout (floats) ----
#define OFF_BP   4194304u    // bf16 packed B fragments (4 MB)
#define OFF_LOG  5242880u    // logits f32 8192*16
#define OFF_G1B  5373952u    // bf16[8192] (gamma-1)
#define OFF_DEN  5378048u    // 4*8192 f32
#define OFF_RS   5410816u    // 4*8192 f32
#define OFF_KC   5443584u    // 64
#define WS_FLOATS 5443648u

typedef short vshort8 __attribute__((ext_vector_type(8)));
typedef float vfloat4 __attribute__((ext_vector_type(4)));

#define AS1 __attribute__((address_space(1)))
#define AS3 __attribute__((address_space(3)))

__device__ __forceinline__ float clip1(float x) {
    return fminf(fmaxf(x, -1.0f + 1e-7f), 1.0f - 1e-7f);
}

__device__ __forceinline__ unsigned short f2bf(float f) {
    unsigned int u = __float_as_uint(f);
    u += 0x7fff + ((u >> 16) & 1);          // round-to-nearest-even
    return (unsigned short)(u >> 16);
}

__device__ __forceinline__ float bf2f(unsigned short b) {
    return __uint_as_float(((unsigned int)b) << 16);
}

__device__ __forceinline__ float waveReduce(float v) {
    #pragma unroll
    for (int off = 32; off; off >>= 1) v += __shfl_down(v, off);
    return v;
}

__device__ __forceinline__ float blockReduceBcast(float v, float* red) {
    int t = threadIdx.x, w = t >> 6, l = t & 63;
    v = waveReduce(v);
    if (l == 0) red[w] = v;
    __syncthreads();
    if (t == 0) red[0] = red[0] + red[1] + red[2] + red[3];
    __syncthreads();
    float r = red[0];
    __syncthreads();
    return r;
}

// ---- K0: per-prototype constants ----
__global__ __launch_bounds__(256) void k_consts(const float* __restrict__ Wl,
                                                const float* __restrict__ Pk,
                                                float* __restrict__ kc) {
    __shared__ float red[8];
    int t = threadIdx.x, k = blockIdx.x;
    float pv = Pk[k * Dd + t];
    float wv = Wl[t * Cc + k];
    float p2 = blockReduceBcast(pv * pv, red);
    float pw = blockReduceBcast(pv * wv, red);
    float w2 = blockReduceBcast(wv * wv, red);
    if (t == 0) {
        float an  = fmaxf(sqrtf(w2), 1e-15f);
        float lam = 2.0f / fmaxf(1.0f - p2, 1e-10f);
        kc[k * 4 + 0] = p2; kc[k * 4 + 1] = pw;
        kc[k * 4 + 2] = an; kc[k * 4 + 3] = lam;
    }
}

// ---- K1: fused X@W^T (bf16 MFMA) + mobius rescale + gamma -> packed B ----
__global__ __launch_bounds__(256) void k_front(const float* __restrict__ X,
                                               const float* __restrict__ W,
                                               unsigned short* __restrict__ Bp,
                                               unsigned short* __restrict__ g1b) {
    __shared__ __align__(16) unsigned short Xs[32][256];
    __shared__ __align__(16) unsigned short Gs[32][258];
    __shared__ float xs2[32];
    __shared__ float scal[32];
    __shared__ float red4[32][4];

    const int t = threadIdx.x;
    const int l = t & 63, w = t >> 6;
    const int ll = l & 15, kh = l >> 4;
    const int m0 = blockIdx.x * 32;
    const int ar = t >> 3, aq = t & 7;
    const int c0 = w * 64;

    float x2p = 0.f;
    #pragma unroll
    for (int tc = 0; tc < 4; ++tc) {
        const float* xp = &X[(size_t)(m0 + ar) * Dd + tc * 64 + aq * 8];
        vfloat4 v0 = *(const vfloat4*)xp;
        vfloat4 v1 = *(const vfloat4*)(xp + 4);
        vshort8 o;
        #pragma unroll
        for (int e = 0; e < 4; ++e) {
            x2p += v0[e] * v0[e] + v1[e] * v1[e];
            o[e] = (short)f2bf(v0[e]);
            o[e + 4] = (short)f2bf(v1[e]);
        }
        int byte = (tc * 64 + aq * 8) * 2;
        *(vshort8*)((char*)&Xs[ar][0] + (byte ^ ((ar & 7) << 4))) = o;
    }
    x2p += __shfl_xor(x2p, 1); x2p += __shfl_xor(x2p, 2); x2p += __shfl_xor(x2p, 4);
    if (aq == 0) xs2[ar] = x2p;
    __syncthreads();

    vfloat4 acc[2][4];
    #pragma unroll
    for (int mi = 0; mi < 2; ++mi)
        #pragma unroll
        for (int ni = 0; ni < 4; ++ni)
            acc[mi][ni] = (vfloat4){0.f, 0.f, 0.f, 0.f};
    #pragma unroll
    for (int tc = 0; tc < 4; ++tc) {
        vshort8 bf[8];
        #pragma unroll
        for (int ni = 0; ni < 4; ++ni)
            #pragma unroll
            for (int kk = 0; kk < 2; ++kk) {
                const float* wp = &W[(size_t)(c0 + ni * 16 + ll) * Dd
                                     + tc * 64 + kh * 8 + kk * 32];
                vfloat4 b0 = *(const vfloat4*)wp;
                vfloat4 b1 = *(const vfloat4*)(wp + 4);
                vshort8 o;
                #pragma unroll
                for (int e = 0; e < 4; ++e) {
                    o[e] = (short)f2bf(b0[e]);
                    o[e + 4] = (short)f2bf(b1[e]);
                }
                bf[ni * 2 + kk] = o;
            }
        #pragma unroll
        for (int kk = 0; kk < 2; ++kk) {
            int byte = (tc * 64 + kh * 8 + kk * 32) * 2;
            vshort8 af[2];
            #pragma unroll
            for (int mi = 0; mi < 2; ++mi) {
                int row = mi * 16 + ll;
                af[mi] = *(const vshort8*)((const char*)&Xs[row][0]
                                           + (byte ^ ((row & 7) << 4)));
            }
            #pragma unroll
            for (int mi = 0; mi < 2; ++mi)
                #pragma unroll
                for (int ni = 0; ni < 4; ++ni)
                    acc[mi][ni] = __builtin_amdgcn_mfma_f32_16x16x32_bf16(
                        af[mi], bf[ni * 2 + kk], acc[mi][ni], 0, 0, 0);
        }
    }

    #pragma unroll
    for (int mi = 0; mi < 2; ++mi)
        #pragma unroll
        for (int j = 0; j < 4; ++j) {
            float p = 0.f;
            #pragma unroll
            for (int ni = 0; ni < 4; ++ni)
                p += acc[mi][ni][j] * acc[mi][ni][j];
            p += __shfl_xor(p, 1); p += __shfl_xor(p, 2);
            p += __shfl_xor(p, 4); p += __shfl_xor(p, 8);
            if (ll == 0) red4[mi * 16 + kh * 4 + j][w] = p;
        }
    __syncthreads();

    if (t < 32) {
        float mx2 = red4[t][0] + red4[t][1] + red4[t][2] + red4[t][3];
        float xn = fmaxf(sqrtf(xs2[t]), 1e-15f);
        float mxn = fmaxf(sqrtf(mx2), 1e-15f);
        float s = tanhf(mxn / xn * atanhf(clip1(xn))) / mxn;
        float xw2 = s * s * mx2;
        float gamma = 2.0f / fmaxf(1.0f - xw2, 1e-10f);
        scal[t] = gamma * s;
        g1b[m0 + t] = f2bf(gamma - 1.0f);
    }
    __syncthreads();

    #pragma unroll
    for (int mi = 0; mi < 2; ++mi)
        #pragma unroll
        for (int ni = 0; ni < 4; ++ni) {
            int row = mi * 16 + kh * 4;
            int col = c0 + ni * 16 + ll;
            #pragma unroll
            for (int j = 0; j < 4; ++j)
                Gs[row + j][col] = f2bf(scal[row + j] * acc[mi][ni][j]);
        }
    __syncthreads();

    const int s = blockIdx.x;
    #pragma unroll
    for (int pass = 0; pass < 4; ++pass) {
        int c = pass * 256 + t;
        int gni = c >> 6, lc = c & 63;
        int col = (gni >> 2) * 64 + (gni & 3) * 16 + (lc & 15);
        int kh8 = (lc >> 4) * 8;
        vshort8 o;
        #pragma unroll
        for (int e = 0; e < 8; ++e) o[e] = (short)Gs[kh8 + e][col];
        *(vshort8*)&Bp[((size_t)(s * 16 + gni) * 64 + lc) * 8] = o;
    }
}

// ======== K2 helpers ========
__device__ __forceinline__ void g2_issueB(const unsigned short* __restrict__ Bp,
        unsigned short (&BsB)[16][512], int splt, int slab, int w, int l) {
    #pragma unroll
    for (int ni = 0; ni < 4; ++ni)
        __builtin_amdgcn_global_load_lds(
            (const AS1 unsigned int*)
                (Bp + ((size_t)((splt * 64 + slab) * 16 + w * 4 + ni) * 512) + l * 8),
            (AS3 unsigned int*)&BsB[w * 4 + ni][0], 16, 0, 0);
}

__device__ __forceinline__ void g2_loadA(const float* __restrict__ Abase,
                                         int tile, float (&a8)[8]) {
    const vfloat4* p = (const vfloat4*)(Abase + tile * 32);
    *(vfloat4*)&a8[0] = p[0];
    *(vfloat4*)&a8[4] = p[1];
}

__device__ __forceinline__ void g2_stage(unsigned short (&AsB)[2048],
        const unsigned short* g1s, const float (&a8)[8],
        int tile, int rowst, int kq, float& dacc, float& racc) {
    vshort8 gv = *(const vshort8*)&g1s[tile * 32 + kq * 8];
    vshort8 o;
    #pragma unroll
    for (int e = 0; e < 8; ++e) {
        float av = a8[e];
        o[e] = (short)f2bf(av);
        dacc += av * bf2f((unsigned short)gv[e]);
        racc += av;
    }
    *(vshort8*)((char*)&AsB[0] + rowst * 64 + ((kq * 16) ^ ((rowst & 3) << 4))) = o;
}

__device__ __forceinline__ void g2_mfma(const unsigned short (&AsB)[2048],
        const unsigned short (&BsB)[16][512], int w, int kh, int ll15, int l,
        vfloat4 (&acc)[4][4]) {
    vshort8 bf[4], af[4];
    #pragma unroll
    for (int ni = 0; ni < 4; ++ni)
        bf[ni] = *(const vshort8*)&BsB[w * 4 + ni][l * 8];
    #pragma unroll
    for (int mi = 0; mi < 4; ++mi) {
        int row = mi * 16 + ll15;
        af[mi] = *(const vshort8*)((const char*)&AsB[0]
                  + row * 64 + ((kh * 16) ^ ((row & 3) << 4)));
    }
    __builtin_amdgcn_s_setprio(1);
    #pragma unroll
    for (int mi = 0; mi < 4; ++mi)
        #pragma unroll
        for (int ni = 0; ni < 4; ++ni)
            acc[mi][ni] = __builtin_amdgcn_mfma_f32_16x16x32_bf16(
                af[mi], bf[ni], acc[mi][ni], 0, 0, 0);
    __builtin_amdgcn_s_setprio(0);
}

// ---- K2: bf16 partials[split] = A(k-slice) @ G ----
// BM=64, BN=256, BK=32, S=4 -> 512 blocks (2/CU). Deep counted pipeline:
// B 4-deep LDS ring issued 3 phases ahead; A 4-deep reg ring issued 4 ahead.
// 6 vmem ops/phase; steady wait vmcnt(18); raw s_barrier; no drain in loop.
__global__ __launch_bounds__(256, 2) void k_gemm1_mfma(
        const float* __restrict__ A,
        const unsigned short* __restrict__ Bp,
        const unsigned short* __restrict__ g1b,
        unsigned short* __restrict__ Pp,
        float* __restrict__ denp,
        float* __restrict__ rsp) {
    __shared__ __align__(16) unsigned short As[2][2048];    // 8 KB
    __shared__ __align__(16) unsigned short Bs[4][16][512]; // 64 KB ring
    __shared__ __align__(16) unsigned short g1s[2048];      // 4 KB

    const int t = threadIdx.x, l = t & 63, w = t >> 6;
    const int id = blockIdx.x;
    const int splt = id & 3;
    const int m0 = (id >> 2) * 64;
    const int kb = splt * 2048;
    const int kh = l >> 4, ll15 = l & 15;
    const int rowst = t >> 2, kq = t & 3;

    const float* Abase = &A[(size_t)(m0 + rowst) * Nn + kb + kq * 8];

    vfloat4 acc[4][4];
    #pragma unroll
    for (int mi = 0; mi < 4; ++mi)
        #pragma unroll
        for (int ni = 0; ni < 4; ++ni)
            acc[mi][ni] = (vfloat4){0.f, 0.f, 0.f, 0.f};
    float dacc = 0.f, racc = 0.f;
    float a0[8], a1[8], a2[8], a3[8];        // A reg ring, distance 4

    // ---- prologue: g1; B slabs 0-2; A tiles 0-3; one-time full drain ----
    uint4 g1v = *(const uint4*)&g1b[kb + t * 8];
    g2_issueB(Bp, Bs[0], splt, 0, w, l);
    g2_issueB(Bp, Bs[1], splt, 1, w, l);
    g2_issueB(Bp, Bs[2], splt, 2, w, l);
    g2_loadA(Abase, 0, a0);
    g2_loadA(Abase, 1, a1);
    g2_loadA(Abase, 2, a2);
    g2_loadA(Abase, 3, a3);
    asm volatile("s_waitcnt vmcnt(0)" ::: "memory");
    *(uint4*)&g1s[t * 8] = g1v;
    asm volatile("s_waitcnt lgkmcnt(0)" ::: "memory");
    __builtin_amdgcn_s_barrier();                        // g1s visible
    g2_stage(As[0], g1s, a0, 0, rowst, kq, dacc, racc);
    asm volatile("s_waitcnt lgkmcnt(0)" ::: "memory");
    __builtin_amdgcn_s_barrier();                        // As[0] visible
    __builtin_amdgcn_sched_barrier(0);

    // ---- 64 phases, unrolled x4 (literal ring indices) ----
    for (int u = 0; u < 16; ++u) {
        #pragma unroll
        for (int pp = 0; pp < 4; ++pp) {
            const int q = u * 4 + pp;
            // issue B(q+3) into ring slot (q+3)&3, A tile (q+4) into areg ring
            g2_issueB(Bp, Bs[(pp + 3) & 3], splt, (q + 3) & 63, w, l);
            {
                float (&adst)[8] = (pp == 0) ? a0 : (pp == 1) ? a1
                                 : (pp == 2) ? a2 : a3;
                g2_loadA(Abase, (q + 4) & 63, adst);
            }
            // steady counted wait: retires B(q) and a(q+1)
            asm volatile("s_waitcnt vmcnt(18)" ::: "memory");
            if (q < 63) {
                float (&asrc)[8] = (pp == 0) ? a1 : (pp == 1) ? a2
                                 : (pp == 2) ? a3 : a0;
                g2_stage(As[(q + 1) & 1], g1s, asrc, q + 1, rowst, kq, dacc, racc);
            }
            g2_mfma(As[q & 1], Bs[pp & 3], w, kh, ll15, l, acc);
            asm volatile("s_waitcnt lgkmcnt(0)" ::: "memory");
            __builtin_amdgcn_s_barrier();
            __builtin_amdgcn_sched_barrier(0);
        }
    }

    // ---- den/rs: 4 staging threads per row are adjacent lanes ----
    dacc += __shfl_xor(dacc, 1); dacc += __shfl_xor(dacc, 2);
    racc += __shfl_xor(racc, 1); racc += __shfl_xor(racc, 2);
    if (kq == 0) {
        denp[splt * Nn + m0 + rowst] = dacc;
        rsp [splt * Nn + m0 + rowst] = racc;
    }

    // ---- store bf16 partial ----
    unsigned short* P = Pp + (size_t)splt * ((size_t)Nn * Dd);
    #pragma unroll
    for (int mi = 0; mi < 4; ++mi)
        #pragma unroll
        for (int ni = 0; ni < 4; ++ni) {
            int row = m0 + mi * 16 + (kh << 2);
            int col = w * 64 + ni * 16 + ll15;
            #pragma unroll
            for (int j = 0; j < 4; ++j)
                P[(size_t)(row + j) * Dd + col] = f2bf(acc[mi][ni][j]);
        }
}

// ---- K3: per-row gyromidpoint chain + H1 + hyperbolic logits ----
__global__ __launch_bounds__(256) void k_rowfix(const unsigned short* __restrict__ Pp,
                                                const float* __restrict__ denp,
                                                const float* __restrict__ rsp,
                                                const float* __restrict__ Pk,
                                                const float* __restrict__ Wl,
                                                const float* __restrict__ kc,
                                                float* __restrict__ logits) {
    __shared__ float red[8];
    __shared__ float hs[256];
    __shared__ float PQ[16][2];
    int i = blockIdx.x, t = threadIdx.x;
    float nom = 0.f;
    #pragma unroll
    for (int s = 0; s < 4; ++s)
        nom += bf2f(Pp[(size_t)s * Nn * Dd + (size_t)i * Dd + t]);
    float dv = denp[i] + denp[Nn + i] + denp[2 * Nn + i] + denp[3 * Nn + i];
    dv = (fabsf(dv) < 1e-10f) ? 1e-10f : dv;
    float tm = nom / dv;
    float r2 = blockReduceBcast(tm * tm, red);
    float r = fmaxf(sqrtf(r2), 1e-15f);
    float mmul = tanhf(0.5f * atanhf(clip1(r))) / r;
    float mj = mmul * tm;
    float mn2 = blockReduceBcast(mj * mj, red);
    float mn = fmaxf(sqrtf(mn2), 1e-15f);
    float sA = rsp[i] + rsp[Nn + i] + rsp[2 * Nn + i] + rsp[3 * Nn + i];
    float axmul = tanhf(sA * atanhf(clip1(mn))) / mn;
    float axw = axmul * mj;
    float yn2 = blockReduceBcast(axw * axw, red);
    float yn = fmaxf(sqrtf(yn2), 1e-15f);
    float v = atanhf(clip1(yn)) / yn * axw;
    float u = fmaxf(v, 0.0f);
    float un2 = blockReduceBcast(u * u, red);
    float un = fmaxf(sqrtf(un2), 1e-15f);
    float h = tanhf(un) / un * u;
    float h2 = blockReduceBcast(h * h, red);
    hs[t] = h;
    __syncthreads();
    int w = t >> 6, l = t & 63;
    #pragma unroll
    for (int kk = 0; kk < 4; ++kk) {
        int k = w * 4 + kk;
        float pp = 0.f, qq = 0.f;
        #pragma unroll
        for (int m = 0; m < 4; ++m) {
            float hv = hs[l + 64 * m];
            pp += hv * Pk[k * Dd + l + 64 * m];
            qq += hv * Wl[(l + 64 * m) * Cc + k];
        }
        pp = waveReduce(pp);
        qq = waveReduce(qq);
        if (l == 0) { PQ[k][0] = pp; PQ[k][1] = qq; }
    }
    __syncthreads();
    if (t < 16) {
        int k = t;
        float p2 = kc[k * 4 + 0], pw = kc[k * 4 + 1];
        float an = kc[k * 4 + 2], lam = kc[k * 4 + 3];
        float P = PQ[k][0], Q = PQ[k][1];
        float alpha = 1.0f - 2.0f * P + h2;
        float beta  = 1.0f - p2;
        float Dm = fmaxf(1.0f - 2.0f * P + p2 * h2, 1e-15f);
        float za  = (-alpha * pw + beta * Q) / Dm;
        float zn2 = (alpha * alpha * p2 - 2.0f * alpha * beta * P + beta * beta * h2)
                    / (Dm * Dm);
        float dd = fmaxf(1.0f - zn2, 1e-10f) * an;
        float dist = asinhf(2.0f * za / dd);
        logits[(size_t)i * Cc + k] = lam * an * dist;
    }
}

// ---- K4: partials of out = A @ logits (j-split x16) ----
__global__ __launch_bounds__(256) void k_gemm2(const float* __restrict__ A,
                                               const float* __restrict__ L,
                                               float* __restrict__ part) {
    __shared__ __align__(16) float Ls[64 * 20];
    __shared__ float Pacc[256 * 16];
    int t = threadIdx.x;
    int r0 = blockIdx.x * 256;
    int jbase = blockIdx.y * 512;
    int q = t & 3, g = t >> 2;
    float acc[4][16] = {};
    for (int jc = 0; jc < 512; jc += 64) {
        {
            int jrow = t >> 2, kq2 = t & 3;
            *(float4*)&Ls[jrow * 20 + kq2 * 4] =
                *(const float4*)&L[(size_t)(jbase + jc + jrow) * Cc + kq2 * 4];
        }
        __syncthreads();
        #pragma unroll
        for (int m = 0; m < 4; ++m) {
            int jl = m * 16 + q * 4;
            float av[4][4];
            #pragma unroll
            for (int rr = 0; rr < 4; ++rr) {
                float4 tmp = *(const float4*)&A[(size_t)(r0 + g * 4 + rr) * Nn
                                                + jbase + jc + jl];
                av[rr][0] = tmp.x; av[rr][1] = tmp.y;
                av[rr][2] = tmp.z; av[rr][3] = tmp.w;
            }
            #pragma unroll
            for (int jj = 0; jj < 4; ++jj) {
                const float* lr = &Ls[(jl + jj) * 20];
                float lv[16];
                #pragma unroll
                for (int k2 = 0; k2 < 16; k2 += 4) {
                    float4 lt = *(const float4*)&lr[k2];
                    lv[k2] = lt.x; lv[k2 + 1] = lt.y;
                    lv[k2 + 2] = lt.z; lv[k2 + 3] = lt.w;
                }
                #pragma unroll
                for (int rr = 0; rr < 4; ++rr)
                    #pragma unroll
                    for (int k2 = 0; k2 < 16; ++k2)
                        acc[rr][k2] += av[rr][jj] * lv[k2];
            }
        }
        __syncthreads();
    }
    for (int ii = t; ii < 4096; ii += 256) Pacc[ii] = 0.f;
    __syncthreads();
    for (int qq = 0; qq < 4; ++qq) {
        if (q == qq) {
            #pragma unroll
            for (int rr = 0; rr < 4; ++rr)
                #pragma unroll
                for (int k2 = 0; k2 < 16; ++k2)
                    Pacc[(g * 4 + rr) * 16 + k2] += acc[rr][k2];
        }
        __syncthreads();
    }
    float* dst = &part[(size_t)blockIdx.y * (Nn * Cc) + (size_t)r0 * Cc];
    for (int ii = t * 4; ii < 4096; ii += 1024)
        *(float4*)&dst[ii] = *(const float4*)&Pacc[ii];
}

// ---- K5: reduce j-split partials ----
__global__ __launch_bounds__(256) void k_reduce(const float* __restrict__ part,
                                                float* __restrict__ out) {
    int i = blockIdx.x * 256 + threadIdx.x;
    float s = 0.f;
    #pragma unroll
    for (int j = 0; j < 16; ++j) s += part[(size_t)j * (Nn * Cc) + i];
    out[i] = s;
}

extern "C" void kernel_launch(void* const* d_in, const int* in_sizes, int n_in,
                              void* d_out, int out_size, void* d_ws, size_t ws_size,
                              hipStream_t stream) {
    const float* X  = (const float*)d_in[0];
    const float* A  = (const float*)d_in[1];
    const float* W  = (const float*)d_in[2];
    const float* Wl = (const float*)d_in[3];
    const float* Pk = (const float*)d_in[4];
    float* out = (float*)d_out;
    float* ws = (float*)d_ws;
    if (ws_size < (size_t)WS_FLOATS * sizeof(float)) return;

    unsigned short* Pp  = (unsigned short*)ws;      // 4 bf16 partials (16MB)
    float* part = ws;                               // gemm2 f32 partials (8MB, later)
    unsigned short* Bp  = (unsigned short*)(ws + OFF_BP);
    float* lg   = ws + OFF_LOG;
    unsigned short* g1b = (unsigned short*)(ws + OFF_G1B);
    float* denp = ws + OFF_DEN;
    float* rsp  = ws + OFF_RS;
    float* kc   = ws + OFF_KC;

    k_consts<<<16, 256, 0, stream>>>(Wl, Pk, kc);
    k_front<<<256, 256, 0, stream>>>(X, W, Bp, g1b);
    k_gemm1_mfma<<<512, 256, 0, stream>>>(A, Bp, g1b, Pp, denp, rsp);
    k_rowfix<<<Nn, 256, 0, stream>>>(Pp, denp, rsp, Pk, Wl, kc, lg);
    k_gemm2<<<dim3(32, 16), 256, 0, stream>>>(A, lg, part);
    k_reduce<<<512, 256, 0, stream>>>(part, out);
}